// Round 9
// baseline (158.464 us; speedup 1.0000x reference)
//
#include <hip/hip_runtime.h>
#include <math.h>

#define G   50
#define T   24
#define B   128
#define NLP (B * T)
#define SZ  (B * G * T)   // 153600 elements per (B,G,T) output

// d_out layout (floats, concatenated in return order):
//   [0,      SZ)        P_DA   (B,G,T)
//   [SZ,     2SZ)       R_up
//   [2SZ,    3SZ)       R_dn
//   [3SZ,    3SZ+B)     obj    (B,)
//   [3SZ+B,  4SZ+B)     Cost_DA

// 12 fused v_add_f32_dpp row_ror (3 chains interleaved): after this every
// lane holds the sum of its 16-lane row for each value. Inputs are fresh
// temps (last use) so the tied "+v" constraints cost no copies. s_nop 1
// guards the producer->DPP-read 2-wait-state hazard at block entry.
__device__ __forceinline__ void rowror_sum3(float& a, float& b, float& c) {
    asm("s_nop 1\n\t"
        "v_add_f32_dpp %0, %0, %0 row_ror:1 row_mask:0xf bank_mask:0xf\n\t"
        "v_add_f32_dpp %1, %1, %1 row_ror:1 row_mask:0xf bank_mask:0xf\n\t"
        "v_add_f32_dpp %2, %2, %2 row_ror:1 row_mask:0xf bank_mask:0xf\n\t"
        "v_add_f32_dpp %0, %0, %0 row_ror:2 row_mask:0xf bank_mask:0xf\n\t"
        "v_add_f32_dpp %1, %1, %1 row_ror:2 row_mask:0xf bank_mask:0xf\n\t"
        "v_add_f32_dpp %2, %2, %2 row_ror:2 row_mask:0xf bank_mask:0xf\n\t"
        "v_add_f32_dpp %0, %0, %0 row_ror:4 row_mask:0xf bank_mask:0xf\n\t"
        "v_add_f32_dpp %1, %1, %1 row_ror:4 row_mask:0xf bank_mask:0xf\n\t"
        "v_add_f32_dpp %2, %2, %2 row_ror:4 row_mask:0xf bank_mask:0xf\n\t"
        "v_add_f32_dpp %0, %0, %0 row_ror:8 row_mask:0xf bank_mask:0xf\n\t"
        "v_add_f32_dpp %1, %1, %1 row_ror:8 row_mask:0xf bank_mask:0xf\n\t"
        "v_add_f32_dpp %2, %2, %2 row_ror:8 row_mask:0xf bank_mask:0xf"
        : "+v"(a), "+v"(b), "+v"(c));
}

// scalar 16-lane row sum (epilogue only)
template <int CTRL>
__device__ __forceinline__ float dpp_mov(float x) {
    int r = __builtin_amdgcn_update_dpp(0, __float_as_int(x), CTRL, 0xf, 0xf, true);
    return __int_as_float(r);
}
__device__ __forceinline__ float row_sum1(float a) {
    a += dpp_mov<0x121>(a);
    a += dpp_mov<0x122>(a);
    a += dpp_mov<0x124>(a);
    a += dpp_mov<0x128>(a);
    return a;
}

// One wave per block; row r = lane>>4 (16 lanes) solves LP (4*blockIdx + r).
// Each lane owns 4 scalar generator slots g = lh + 16*s, s=0..3
// (slot 3 valid iff lh < 2). Sentinel BIG cost clamps invalid slots to 0.
__global__ __launch_bounds__(64)
void pdhg_lp_kernel(const float* __restrict__ forecast,
                    const float* __restrict__ pmin,
                    const float* __restrict__ pmax,
                    const float* __restrict__ bcost,
                    const float* __restrict__ ccost,
                    const int*   __restrict__ n_iters_p,
                    float* __restrict__ out,
                    float* __restrict__ ws_partial,   // NLP floats (or null)
                    float tau)
{
    const int lane = threadIdx.x;         // 0..63
    const int lh   = lane & 15;           // lane within row
    const int row  = lane >> 4;           // LP slot within wave
    const int lp   = blockIdx.x * 4 + row;
    const int b    = lp / T;
    const int t    = lp - b * T;
    const int n_iters = n_iters_p[0];

    const float f   = forecast[lp];       // uniform within each row
    const float ts  = tau * tau;          // sigma == tau
    const float BIG = 1e30f;              // sentinel: keeps invalid slot at 0

    float bj[4], cj[4], tcP[4], tcRu[4], tcRd[4], tspmx[4], tspmn[4];
    #pragma unroll
    for (int s = 0; s < 4; ++s) {
        const int  g = lh + 16 * s;
        const bool v = (g < G);
        const int  gc = v ? g : 0;
        const float bs = v ? bcost[gc] : 0.f;
        bj[s]    = bs;
        cj[s]    = v ? ccost[gc] : 0.f;
        tcP[s]   = v ? tau * bs         : BIG;
        tcRu[s]  = v ? tau * 0.05f * bs : BIG;
        tcRd[s]  = v ? tau * 0.02f * bs : BIG;
        tspmx[s] = v ? ts * pmax[gc] : 0.f;
        tspmn[s] = v ? ts * pmin[gc] : 0.f;
    }
    const float tsf   = ts * f;
    const float tsreq = ts * 0.02f * f;   // REQ_UP_RATIO == REQ_DN_RATIO

    // state: primal P,Ru,Rd; duals z1,z3 (>=0), negated nz2,nz4 (<=0), all
    // scaled by tau; row-uniform z0,zru,zrd replicated per lane.
    float P[4]  = {0,0,0,0}, Ru[4]  = {0,0,0,0}, Rd[4]  = {0,0,0,0};
    float z1[4] = {0,0,0,0}, nz2[4] = {0,0,0,0};
    float z3[4] = {0,0,0,0}, nz4[4] = {0,0,0,0};
    float z0 = 0.f, zru = 0.f, zrd = 0.f;

    for (int it = 0; it < n_iters; ++it) {
        float Pb[4], Rub[4], Rdb[4];
        // ---- x-update + overrelaxation (all scalar, per slot) ----
        #pragma unroll
        for (int s = 0; s < 4; ++s) {
            float gP  = ((z0 + z1[s]) + (nz2[s] + z3[s])) + nz4[s];
            float Pn  = fmaxf(P[s] - (tcP[s] + gP), 0.f);
            float Run = fmaxf(((Ru[s] - z1[s]) + zru) - tcRu[s], 0.f);
            float Rdn = fmaxf(((Rd[s] + nz2[s]) + zrd) - tcRd[s], 0.f);
            Pb[s]  = fmaf(2.f, Pn,  -P[s]);
            Rub[s] = fmaf(2.f, Run, -Ru[s]);
            Rdb[s] = fmaf(2.f, Rdn, -Rd[s]);
            P[s] = Pn; Ru[s] = Run; Rd[s] = Rdn;
        }

        // ---- 16-lane row sums: slot fold + fused DPP (fresh temps) ----
        float sP  = (Pb[0]  + Pb[1])  + (Pb[2]  + Pb[3]);
        float sRu = (Rub[0] + Rub[1]) + (Rub[2] + Rub[3]);
        float sRd = (Rdb[0] + Rdb[1]) + (Rdb[2] + Rdb[3]);
        rowror_sum3(sP, sRu, sRd);

        // ---- per-lane z-updates (independent of the sums) ----
        #pragma unroll
        for (int s = 0; s < 4; ++s) {
            z1[s]  = fmaxf(fmaf(ts, Pb[s] + Rub[s], z1[s])  - tspmx[s], 0.f);
            nz2[s] = fminf(fmaf(ts, Pb[s] - Rdb[s], nz2[s]) - tspmn[s], 0.f);
            z3[s]  = fmaxf(fmaf(ts, Pb[s], z3[s])  - tspmx[s], 0.f);
            nz4[s] = fminf(fmaf(ts, Pb[s], nz4[s]) - tspmn[s], 0.f);
        }

        // ---- row-uniform rows (consume completed sums) ----
        z0  = fmaf(ts, sP, z0) - tsf;
        zru = fmaxf(fmaf(-ts, sRu, zru + tsreq), 0.f);
        zrd = fmaxf(fmaf(-ts, sRd, zrd + tsreq), 0.f);
    }

    // ---- epilogue: outputs + objective partial ----
    {
        const int bgt = b * (G * T) + t;
        #pragma unroll
        for (int s = 0; s < 4; ++s) {
            const int g = lh + 16 * s;
            if (g < G) {
                const int i = bgt + g * T;
                out[i]              = P[s];
                out[SZ + i]         = Ru[s];
                out[2 * SZ + i]     = Rd[s];
                out[3 * SZ + B + i] = bj[s] * P[s] + cj[s];
            }
        }
    }

    if (ws_partial) {
        // sum_g cost + 0.05*b*Ru + 0.02*b*Rd  (invalid slots contribute 0)
        float lo = 0.f;
        #pragma unroll
        for (int s = 0; s < 4; ++s)
            lo += (bj[s] * P[s] + cj[s])
                + 0.05f * bj[s] * Ru[s] + 0.02f * bj[s] * Rd[s];
        float tot = row_sum1(lo);
        if (lh == 0) ws_partial[lp] = tot;
    }
}

// obj[b] = sum_t ws_partial[b*T + t]   (deterministic, tiny)
__global__ __launch_bounds__(64)
void obj_final_kernel(const float* __restrict__ ws_partial, float* __restrict__ out)
{
    const int b = blockIdx.x * 64 + threadIdx.x;
    if (b < B) {
        float s = 0.f;
        #pragma unroll
        for (int t = 0; t < T; ++t) s += ws_partial[b * T + t];
        out[3 * SZ + b] = s;
    }
}

// Fallback (ws too small): recompute obj from outputs, one block per b
__global__ __launch_bounds__(256)
void obj_kernel(const float* __restrict__ bcost, float* __restrict__ out)
{
    const int b = blockIdx.x;
    const float* Ru = out + SZ     + (size_t)b * (G * T);
    const float* Rd = out + 2 * SZ + (size_t)b * (G * T);
    const float* C  = out + 3 * SZ + B + (size_t)b * (G * T);

    float s = 0.f;
    for (int i = threadIdx.x; i < G * T; i += 256) {
        const int g = i / T;
        const float bg = bcost[g];
        s += C[i] + 0.05f * bg * Ru[i] + 0.02f * bg * Rd[i];
    }
    s = row_sum1(s);                                 // 16-lane row sums
    __shared__ float sm[16];
    if ((threadIdx.x & 15) == 0) sm[threadIdx.x >> 4] = s;
    __syncthreads();
    if (threadIdx.x == 0) {
        float tot = 0.f;
        #pragma unroll
        for (int i = 0; i < 16; ++i) tot += sm[i];
        out[3 * SZ + b] = tot;
    }
}

extern "C" void kernel_launch(void* const* d_in, const int* in_sizes, int n_in,
                              void* d_out, int out_size, void* d_ws, size_t ws_size,
                              hipStream_t stream) {
    const float* forecast = (const float*)d_in[0];
    const float* pmin_p   = (const float*)d_in[1];
    const float* pmax_p   = (const float*)d_in[2];
    const float* b_p      = (const float*)d_in[3];
    const float* c_p      = (const float*)d_in[4];
    const int*   niter_p  = (const int*)  d_in[5];
    float* out = (float*)d_out;

    // ||K||_2 analytic for this fixed 0/±1 structure (G=50):
    // K^T K = [[4I+J, I, -I],[I, I+J, 0],[-I, 0, I+J]]; largest eig on the
    // ones-subspace is (105+sqrt(17))/2  ->  L = sqrt((105+sqrt(17))/2)
    const double L = sqrt((105.0 + sqrt(17.0)) * 0.5);
    const float tau = (float)(0.9 / L);   // sigma == tau

    const bool use_ws = (ws_size >= (size_t)NLP * sizeof(float));
    float* wsp = use_ws ? (float*)d_ws : nullptr;

    pdhg_lp_kernel<<<NLP / 4, 64, 0, stream>>>(forecast, pmin_p, pmax_p,
                                               b_p, c_p, niter_p, out, wsp, tau);
    if (use_ws) {
        obj_final_kernel<<<(B + 63) / 64, 64, 0, stream>>>(wsp, out);
    } else {
        obj_kernel<<<B, 256, 0, stream>>>(b_p, out);
    }
}

// Round 10
// 136.351 us; speedup vs baseline: 1.1622x; 1.1622x over previous
//
#include <hip/hip_runtime.h>
#include <math.h>

#define G   50
#define T   24
#define B   128
#define NLP (B * T)
#define SZ  (B * G * T)   // 153600 elements per (B,G,T) output

typedef float v2f __attribute__((ext_vector_type(2)));

// d_out layout (floats, concatenated in return order):
//   [0,      SZ)        P_DA   (B,G,T)
//   [SZ,     2SZ)       R_up
//   [2SZ,    3SZ)       R_dn
//   [3SZ,    3SZ+B)     obj    (B,)
//   [3SZ+B,  4SZ+B)     Cost_DA

__device__ __forceinline__ v2f vmax0(v2f v) {
    v2f z = {0.f, 0.f};
    return __builtin_elementwise_max(v, z);
}

// DPP helper (epilogue only)
template <int CTRL>
__device__ __forceinline__ float dpp_mov(float x) {
    int r = __builtin_amdgcn_update_dpp(0, __float_as_int(x), CTRL, 0xf, 0xf, true);
    return __int_as_float(r);
}

// All-reduce 3 values within each 16-lane ROW — 12 fused v_add_f32_dpp,
// chains interleaved (>=2 intervening instrs between write and DPP read).
// s_nop 1 guards the producer->DPP-read hazard at block entry.
__device__ __forceinline__ void row_sum3(float& a, float& b, float& c) {
    asm("s_nop 1\n\t"
        "v_add_f32_dpp %0, %0, %0 row_ror:1 row_mask:0xf bank_mask:0xf\n\t"
        "v_add_f32_dpp %1, %1, %1 row_ror:1 row_mask:0xf bank_mask:0xf\n\t"
        "v_add_f32_dpp %2, %2, %2 row_ror:1 row_mask:0xf bank_mask:0xf\n\t"
        "v_add_f32_dpp %0, %0, %0 row_ror:2 row_mask:0xf bank_mask:0xf\n\t"
        "v_add_f32_dpp %1, %1, %1 row_ror:2 row_mask:0xf bank_mask:0xf\n\t"
        "v_add_f32_dpp %2, %2, %2 row_ror:2 row_mask:0xf bank_mask:0xf\n\t"
        "v_add_f32_dpp %0, %0, %0 row_ror:4 row_mask:0xf bank_mask:0xf\n\t"
        "v_add_f32_dpp %1, %1, %1 row_ror:4 row_mask:0xf bank_mask:0xf\n\t"
        "v_add_f32_dpp %2, %2, %2 row_ror:4 row_mask:0xf bank_mask:0xf\n\t"
        "v_add_f32_dpp %0, %0, %0 row_ror:8 row_mask:0xf bank_mask:0xf\n\t"
        "v_add_f32_dpp %1, %1, %1 row_ror:8 row_mask:0xf bank_mask:0xf\n\t"
        "v_add_f32_dpp %2, %2, %2 row_ror:8 row_mask:0xf bank_mask:0xf"
        : "+v"(a), "+v"(b), "+v"(c));
}

__device__ __forceinline__ float row_sum1(float a) {
    a += dpp_mov<0x121>(a);
    a += dpp_mov<0x122>(a);
    a += dpp_mov<0x124>(a);
    a += dpp_mov<0x128>(a);
    return a;
}

// One wave per block; row r = lane>>4 (16 lanes) solves LP (4*blockIdx + r).
// Each lane owns generators {lh, lh+16} (v2f A) and {lh+32, lh+48} (v2f B;
// B.y valid iff lh<2). 50 gens total, sentinel cost clamps invalid slots.
// __launch_bounds__(64, 1): only 0.75 waves/SIMD ever run -> give the
// register allocator the full budget so loop-invariant v2f constants stay
// resident (VGPR_Count was 40 = rematerialization inside the K-loop).
__global__ __launch_bounds__(64, 1)
void pdhg_lp_kernel(const float* __restrict__ forecast,
                    const float* __restrict__ pmin,
                    const float* __restrict__ pmax,
                    const float* __restrict__ bcost,
                    const float* __restrict__ ccost,
                    const int*   __restrict__ n_iters_p,
                    float* __restrict__ out,
                    float* __restrict__ ws_partial,   // NLP floats (or null)
                    float tau)
{
    const int lane = threadIdx.x;         // 0..63
    const int lh   = lane & 15;           // lane within row
    const int row  = lane >> 4;           // LP slot within wave
    const int lp   = blockIdx.x * 4 + row;
    const int b    = lp / T;
    const int t    = lp - b * T;
    const int n_iters = n_iters_p[0];

    const int  gA0 = lh,      gA1 = lh + 16;   // always < 50
    const int  gB0 = lh + 32;                  // always < 50
    const int  gB1 = lh + 48;                  // valid iff lh < 2
    const bool vB1 = (lh < 2);

    v2f bjA  = { bcost[gA0], bcost[gA1] };
    v2f bjB  = { bcost[gB0], vB1 ? bcost[gB1] : 0.f };
    v2f cjA  = { ccost[gA0], ccost[gA1] };
    v2f cjB  = { ccost[gB0], vB1 ? ccost[gB1] : 0.f };
    v2f pmxA = { pmax[gA0],  pmax[gA1] };
    v2f pmxB = { pmax[gB0],  vB1 ? pmax[gB1] : 0.f };
    v2f pmnA = { pmin[gA0],  pmin[gA1] };
    v2f pmnB = { pmin[gB0],  vB1 ? pmin[gB1] : 0.f };
    const float f = forecast[lp];         // uniform within each row

    const float ts  = tau * tau;          // sigma == tau
    const float BIG = 1e30f;              // sentinel: clamps invalid slot to 0

    v2f tcPA  = tau * bjA;
    v2f tcPB  = tau * bjB;           if (!vB1) tcPB.y  = BIG;
    v2f tcRuA = (tau * 0.05f) * bjA;
    v2f tcRuB = (tau * 0.05f) * bjB; if (!vB1) tcRuB.y = BIG;
    v2f tcRdA = (tau * 0.02f) * bjA;
    v2f tcRdB = (tau * 0.02f) * bjB; if (!vB1) tcRdB.y = BIG;
    v2f tspmxA = ts * pmxA, tspmxB = ts * pmxB;
    v2f tspmnA = ts * pmnA, tspmnB = ts * pmnB;
    const float tsf   = ts * f;
    const float tsreq = ts * 0.02f * f;   // REQ_UP_RATIO == REQ_DN_RATIO

    v2f PA = {0,0}, PB = {0,0}, RuA = {0,0}, RuB = {0,0}, RdA = {0,0}, RdB = {0,0};
    v2f z1A = {0,0}, z1B = {0,0}, z2A = {0,0}, z2B = {0,0};
    v2f z3A = {0,0}, z3B = {0,0}, z4A = {0,0}, z4B = {0,0};   // scaled duals tau*y
    float z0 = 0.f, zru = 0.f, zrd = 0.f;                     // row-uniform

    for (int it = 0; it < n_iters; ++it) {
        // ---- x-update: x_new = max(x - (tau*c + tau*K^T y), 0) ----
        v2f z0v = { z0, z0 };
        v2f zruv = { zru, zru };
        v2f zrdv = { zrd, zrd };
        v2f gPA = (z1A - z2A) + (z3A - z4A) + z0v;
        v2f gPB = (z1B - z2B) + (z3B - z4B) + z0v;
        v2f PnA = vmax0(PA - tcPA - gPA);
        v2f PnB = vmax0(PB - tcPB - gPB);
        v2f RunA = vmax0(RuA - tcRuA - z1A + zruv);
        v2f RunB = vmax0(RuB - tcRuB - z1B + zruv);
        v2f RdnA = vmax0(RdA - tcRdA - z2A + zrdv);
        v2f RdnB = vmax0(RdB - tcRdB - z2B + zrdv);

        // overrelaxation: x_bar = 2*x_new - x_old
        v2f PbA  = 2.f * PnA  - PA,  PbB  = 2.f * PnB  - PB;
        v2f RubA = 2.f * RunA - RuA, RubB = 2.f * RunB - RuB;
        v2f RdbA = 2.f * RdnA - RdA, RdbB = 2.f * RdnB - RdB;
        PA = PnA; PB = PnB; RuA = RunA; RuB = RunB; RdA = RdnA; RdB = RdnB;

        // ---- row-local sums over generators (fused DPP adds, no LDS) ----
        v2f tP = PbA + PbB, tRu = RubA + RubB, tRd = RdbA + RdbB;
        float sP  = tP.x  + tP.y;
        float sRu = tRu.x + tRu.y;
        float sRd = tRd.x + tRd.y;
        row_sum3(sP, sRu, sRd);

        // ---- z-update: z += tau*sigma*(K x_bar - q), clamp ineq rows ----
        z0  = z0 + ts * sP - tsf;                             // equality row
        z1A = vmax0(z1A + ts * (PbA + RubA) - tspmxA);        // P+Ru <= pmax
        z1B = vmax0(z1B + ts * (PbB + RubB) - tspmxB);
        z2A = vmax0(z2A + ts * (RdbA - PbA) + tspmnA);        // -P+Rd <= -pmin
        z2B = vmax0(z2B + ts * (RdbB - PbB) + tspmnB);
        z3A = vmax0(z3A + ts * PbA - tspmxA);                 // P <= pmax
        z3B = vmax0(z3B + ts * PbB - tspmxB);
        z4A = vmax0(z4A - ts * PbA + tspmnA);                 // -P <= -pmin
        z4B = vmax0(z4B - ts * PbB + tspmnB);
        zru = fmaxf(zru + tsreq - ts * sRu, 0.f);             // -sum Ru <= -req
        zrd = fmaxf(zrd + tsreq - ts * sRd, 0.f);             // -sum Rd <= -req
    }

    const v2f costA = bjA * PA + cjA;
    const v2f costB = bjB * PB + cjB;
    {
        const int bgt = b * (G * T) + t;
        const int a0 = bgt + gA0 * T, a1 = bgt + gA1 * T, b0 = bgt + gB0 * T;
        out[a0] = PA.x;  out[SZ + a0] = RuA.x;  out[2*SZ + a0] = RdA.x;  out[3*SZ + B + a0] = costA.x;
        out[a1] = PA.y;  out[SZ + a1] = RuA.y;  out[2*SZ + a1] = RdA.y;  out[3*SZ + B + a1] = costA.y;
        out[b0] = PB.x;  out[SZ + b0] = RuB.x;  out[2*SZ + b0] = RdB.x;  out[3*SZ + B + b0] = costB.x;
        if (vB1) {
            const int b1 = bgt + gB1 * T;
            out[b1] = PB.y;  out[SZ + b1] = RuB.y;  out[2*SZ + b1] = RdB.y;  out[3*SZ + B + b1] = costB.y;
        }
    }

    if (ws_partial) {
        // per-(b,t) objective partial: sum_g cost + 0.05*b*Ru + 0.02*b*Rd
        v2f lo = costA + (0.05f * bjA) * RuA + (0.02f * bjA) * RdA
               + costB + (0.05f * bjB) * RuB + (0.02f * bjB) * RdB;
        float tot = row_sum1(lo.x + lo.y);
        if (lh == 0) ws_partial[lp] = tot;
    }
}

// obj[b] = sum_t ws_partial[b*T + t]   (deterministic, tiny)
__global__ __launch_bounds__(64)
void obj_final_kernel(const float* __restrict__ ws_partial, float* __restrict__ out)
{
    const int b = blockIdx.x * 64 + threadIdx.x;
    if (b < B) {
        float s = 0.f;
        #pragma unroll
        for (int t = 0; t < T; ++t) s += ws_partial[b * T + t];
        out[3 * SZ + b] = s;
    }
}

// Fallback (ws too small): recompute obj from outputs, one block per b
__global__ __launch_bounds__(256)
void obj_kernel(const float* __restrict__ bcost, float* __restrict__ out)
{
    const int b = blockIdx.x;
    const float* Ru = out + SZ     + (size_t)b * (G * T);
    const float* Rd = out + 2 * SZ + (size_t)b * (G * T);
    const float* C  = out + 3 * SZ + B + (size_t)b * (G * T);

    float s = 0.f;
    for (int i = threadIdx.x; i < G * T; i += 256) {
        const int g = i / T;
        const float bg = bcost[g];
        s += C[i] + 0.05f * bg * Ru[i] + 0.02f * bg * Rd[i];
    }
    s = row_sum1(s);                                 // 16-lane row sums
    __shared__ float sm[16];
    if ((threadIdx.x & 15) == 0) sm[threadIdx.x >> 4] = s;
    __syncthreads();
    if (threadIdx.x == 0) {
        float tot = 0.f;
        #pragma unroll
        for (int i = 0; i < 16; ++i) tot += sm[i];
        out[3 * SZ + b] = tot;
    }
}

extern "C" void kernel_launch(void* const* d_in, const int* in_sizes, int n_in,
                              void* d_out, int out_size, void* d_ws, size_t ws_size,
                              hipStream_t stream) {
    const float* forecast = (const float*)d_in[0];
    const float* pmin_p   = (const float*)d_in[1];
    const float* pmax_p   = (const float*)d_in[2];
    const float* b_p      = (const float*)d_in[3];
    const float* c_p      = (const float*)d_in[4];
    const int*   niter_p  = (const int*)  d_in[5];
    float* out = (float*)d_out;

    // ||K||_2 analytic for this fixed 0/±1 structure (G=50):
    // K^T K = [[4I+J, I, -I],[I, I+J, 0],[-I, 0, I+J]]; largest eig on the
    // ones-subspace is (105+sqrt(17))/2  ->  L = sqrt((105+sqrt(17))/2)
    const double L = sqrt((105.0 + sqrt(17.0)) * 0.5);
    const float tau = (float)(0.9 / L);   // sigma == tau

    const bool use_ws = (ws_size >= (size_t)NLP * sizeof(float));
    float* wsp = use_ws ? (float*)d_ws : nullptr;

    pdhg_lp_kernel<<<NLP / 4, 64, 0, stream>>>(forecast, pmin_p, pmax_p,
                                               b_p, c_p, niter_p, out, wsp, tau);
    if (use_ws) {
        obj_final_kernel<<<(B + 63) / 64, 64, 0, stream>>>(wsp, out);
    } else {
        obj_kernel<<<B, 256, 0, stream>>>(b_p, out);
    }
}